// Round 20
// baseline (184.419 us; speedup 1.0000x reference)
//
#include <hip/hip_runtime.h>
#include <hip/hip_bf16.h>
#include <math.h>

#define HID 4096
#define NH 32
#define HD 128
#define EDGE 24
#define KW 12
#define PEW 13
#define VT 576
#define OFF 5
#define NB 2
#define SLEN 1024
#define QT 64      // q rows per scores block
#define NQT 7      // q tiles per (b,h)  (448/64)
#define KT 64      // k rows per staged tile
#define NKT 16     // 1024/KT
#define NSB 448    // scores blocks (64 bh x 7 qt)
#define NWB 128    // W-convert blocks folded into k_scores' grid

typedef short bf16x8 __attribute__((ext_vector_type(8)));
typedef float f32x4 __attribute__((ext_vector_type(4)));
typedef unsigned int u32;

static __device__ __forceinline__ unsigned short f2bf(float f) {
  union { float f; u32 u; } v; v.f = f;
  u32 u = v.u;
  return (unsigned short)((u + 0x7fffu + ((u >> 16) & 1u)) >> 16);
}

static __device__ __forceinline__ float dot4(float4 a, float4 b) {
  return a.x * b.x + a.y * b.y + a.z * b.z + a.w * b.w;
}

static __device__ __forceinline__ void load_lds16(const void* g, void* l) {
  __builtin_amdgcn_global_load_lds((const __attribute__((address_space(1))) u32*)g,
                                   (__attribute__((address_space(3))) u32*)l, 16, 0, 0);
}

// ---------------- Kernel PREP: hidden -> hi/lo bf16 planes (grid-stride) ----------------
__global__ __launch_bounds__(256) void k_prep(const float* __restrict__ hid,
                                              unsigned short* __restrict__ Phi,
                                              unsigned short* __restrict__ Plo) {
  const int STR = 2048 * 256;
  int t0 = blockIdx.x * 256 + threadIdx.x;
  for (int i = t0; i < NB * SLEN * HID / 4; i += STR) {
    float4 x = ((const float4*)hid)[i];
    float e[4] = {x.x, x.y, x.z, x.w};
    ushort4 hv, lv;
    unsigned short* hp = (unsigned short*)&hv;
    unsigned short* lp = (unsigned short*)&lv;
#pragma unroll
    for (int j = 0; j < 4; ++j) {
      u32 u = __float_as_uint(e[j]);
      u32 hb = (u + 0x7fffu + ((u >> 16) & 1u)) >> 16;
      float r = e[j] - __uint_as_float(hb << 16);
      u32 ur = __float_as_uint(r);
      u32 lb = (ur + 0x7fffu + ((ur >> 16) & 1u)) >> 16;
      hp[j] = (unsigned short)hb;
      lp[j] = (unsigned short)lb;
    }
    ((ushort4*)Phi)[i] = hv;
    int s = (i >> 10) & (SLEN - 1);
    if (s < OFF || s >= OFF + VT) ((ushort4*)Plo)[i] = lv;
  }
}

// ---------------- Kernel B: single-pass 8-wave MFMA scores (2-chain) + W-convert ----------------
__global__ __launch_bounds__(512, 2) void k_scores(const unsigned short* __restrict__ Phi,
                                                   const unsigned short* __restrict__ Plo,
                                                   float* __restrict__ part,
                                                   const float* __restrict__ Win,
                                                   unsigned short* __restrict__ Wb) {
  __shared__ unsigned short Kh[3][KT * HD];   // 48 KB
  __shared__ float cs[4][SLEN];               // 16 KB
  __shared__ float zbuf[2][QT];               // 512 B

  int bid = blockIdx.x;
  int t = threadIdx.x;

  if (bid >= NSB) {
    int base = (bid - NSB) * 32768;
#pragma unroll 4
    for (int it = 0; it < 64; ++it) {
      int i = base + it * 512 + t;
      float4 v = ((const float4*)Win)[i];
      ushort4 o;
      o.x = f2bf(v.x); o.y = f2bf(v.y); o.z = f2bf(v.z); o.w = f2bf(v.w);
      ((ushort4*)Wb)[i] = o;
    }
    return;
  }

  int xcd = bid & 7, idx = bid >> 3;          // idx in 0..55
  int bh = xcd * 8 + idx / NQT;
  int qt = idx % NQT;
  int b = bh >> 5, h = bh & 31;
  int l = t & 63, wv = t >> 6;
  int wq = wv >> 1, wk = wv & 1;

  const unsigned short* PhB = Phi + (size_t)b * SLEN * HID + h * HD;
  const unsigned short* PlB = Plo + (size_t)b * SLEN * HID + h * HD;

  bf16x8 qhi[4], qlo[4];
  {
    int ql = qt * QT + wq * 16 + (l & 15);
    int qg = (ql < OFF) ? ql : ql + VT;
    const unsigned short* ph = PhB + (size_t)qg * HID + (l >> 4) * 8;
    const unsigned short* pl = PlB + (size_t)qg * HID + (l >> 4) * 8;
#pragma unroll
    for (int ds = 0; ds < 4; ++ds) {
      qhi[ds] = *(const bf16x8*)(ph + ds * 32);
      qlo[ds] = *(const bf16x8*)(pl + ds * 32);
    }
  }

  int g0 = t, g1 = t + 512;
  int r0g = g0 >> 4, r1g = g1 >> 4;
  size_t soff0 = (size_t)r0g * HID + ((g0 & 15) ^ (r0g & 7)) * 8;
  size_t soff1 = (size_t)r1g * HID + ((g1 & 15) ^ (r1g & 7)) * 8;

#define STAGE(kt_, bb_)                                                        \
  do {                                                                         \
    size_t kb_ = (size_t)(kt_)*KT * HID;                                       \
    load_lds16(PhB + kb_ + soff0, &Kh[bb_][g0 * 8]);                           \
    load_lds16(PhB + kb_ + soff1, &Kh[bb_][g1 * 8]);                           \
  } while (0)

  const float scale = 0.088388347648318447f;  // 1/sqrt(128)

  int foff[2][4];
#pragma unroll
  for (int c = 0; c < 2; ++c) {
    int rb = wk * 32 + c * 16 + (l & 15);
#pragma unroll
    for (int ds = 0; ds < 4; ++ds)
      foff[c][ds] = rb * HD + (((ds * 4) + (l >> 4)) ^ (rb & 7)) * 8;
  }

  float e[NKT][2][4];

  STAGE(0, 0);
  STAGE(1, 1);

#pragma unroll
  for (int tt = 0; tt < NKT; ++tt) {
    int bb = tt % 3;
    if (tt < NKT - 1) {
      asm volatile("s_waitcnt vmcnt(2)" ::: "memory");
    } else {
      asm volatile("s_waitcnt vmcnt(0)" ::: "memory");
    }
    __builtin_amdgcn_s_barrier();
    __builtin_amdgcn_sched_barrier(0);

    bf16x8 kh[2][4];
#pragma unroll
    for (int c = 0; c < 2; ++c)
#pragma unroll
      for (int ds = 0; ds < 4; ++ds)
        kh[c][ds] = *(const bf16x8*)&Kh[bb][foff[c][ds]];
    if (tt + 2 < NKT) STAGE(tt + 2, (tt + 2) % 3);

#pragma unroll
    for (int c = 0; c < 2; ++c) {
      f32x4 aP = {0.f, 0.f, 0.f, 0.f};
      f32x4 aR = {0.f, 0.f, 0.f, 0.f};
#pragma unroll
      for (int ds = 0; ds < 4; ++ds) {
        aP = __builtin_amdgcn_mfma_f32_16x16x32_bf16(qhi[ds], kh[c][ds], aP, 0, 0, 0);
        aR = __builtin_amdgcn_mfma_f32_16x16x32_bf16(qlo[ds], kh[c][ds], aR, 0, 0, 0);
      }
#pragma unroll
      for (int jj = 0; jj < 4; ++jj)
        e[tt][c][jj] = __expf((aP[jj] + aR[jj]) * scale);
    }
  }
#undef STAGE

  float zr[4] = {0.f, 0.f, 0.f, 0.f};
#pragma unroll
  for (int tt = 0; tt < NKT; ++tt)
#pragma unroll
    for (int c = 0; c < 2; ++c)
#pragma unroll
      for (int jj = 0; jj < 4; ++jj) zr[jj] += e[tt][c][jj];
#pragma unroll
  for (int jj = 0; jj < 4; ++jj) {
    float z = zr[jj];
    z += __shfl_xor(z, 1);
    z += __shfl_xor(z, 2);
    z += __shfl_xor(z, 4);
    z += __shfl_xor(z, 8);
    zr[jj] = z;
  }
  if ((l & 15) == 0) {
#pragma unroll
    for (int jj = 0; jj < 4; ++jj)
      zbuf[wk][wq * 16 + (l >> 4) * 4 + jj] = zr[jj];
  }
  __syncthreads();

  float zinv[4];
#pragma unroll
  for (int jj = 0; jj < 4; ++jj) {
    int row = wq * 16 + (l >> 4) * 4 + jj;
    zinv[jj] = 1.f / (zbuf[0][row] + zbuf[1][row]);
  }

#pragma unroll
  for (int tt = 0; tt < NKT; ++tt)
#pragma unroll
    for (int c = 0; c < 2; ++c) {
      float v = e[tt][c][0] * zinv[0] + e[tt][c][1] * zinv[1] +
                e[tt][c][2] * zinv[2] + e[tt][c][3] * zinv[3];
      v += __shfl_xor(v, 16);
      v += __shfl_xor(v, 32);
      if (l < 16) cs[wq][tt * KT + wk * 32 + c * 16 + l] = v;
    }
  __syncthreads();

  for (int c5 = t; c5 < VT; c5 += 512) {
    int col = OFF + c5;
    part[((size_t)bh * NQT + qt) * VT + c5] =
        (cs[0][col] + cs[1][col]) + (cs[2][col] + cs[3][col]);
  }
}

// ---------------- Kernel D: fused head-reduce + window up-projection ----------------
__global__ __launch_bounds__(256) void k_himg(const float* __restrict__ part,
                                              const float* __restrict__ hid,
                                              const float* __restrict__ Wup,
                                              unsigned short* __restrict__ hs) {
  int bid = blockIdx.x;
  int g = bid & 3;
  int bh = bid >> 2;
  int b = bh / NH, h = bh % NH;
  int t = threadIdx.x;

  __shared__ float ia[VT];
  __shared__ float sfe[VT];
  __shared__ float rbuf[256];
  __shared__ int ribuf[256];
  __shared__ float win[36][HD];

  for (int i = t; i < VT; i += 256) {
    float s = 0.f;
    const float* p = part + (size_t)bh * NQT * VT + i;
    for (int c = 0; c < NQT; ++c) s += p[(size_t)c * VT];
    ia[i] = s;
  }
  __syncthreads();

  float lm = -1e30f;
  for (int i = t; i < VT; i += 256) lm = fmaxf(lm, ia[i]);
  rbuf[t] = lm;
  __syncthreads();
  for (int s = 128; s > 0; s >>= 1) {
    if (t < s) rbuf[t] = fmaxf(rbuf[t], rbuf[t + s]);
    __syncthreads();
  }
  float M = rbuf[0];
  __syncthreads();

  float lz = 0.f;
  for (int i = t; i < VT; i += 256) {
    float e = __expf(ia[i] - M);
    sfe[i] = e;
    lz += e;
  }
  rbuf[t] = lz;
  __syncthreads();
  for (int s = 128; s > 0; s >>= 1) {
    if (t < s) rbuf[t] += rbuf[t + s];
    __syncthreads();
  }
  float invZ = 1.f / rbuf[0];
  __syncthreads();

  float pv = -1e30f;
  int pidx = 0x7fffffff;
  if (t < PEW * PEW) {
    int r = t / PEW, c = t % PEW;
    float s = 0.f;
    for (int i = 0; i < KW; ++i)
      for (int j = 0; j < KW; ++j) s += ia[(r + i) * EDGE + (c + j)];
    pv = s;
    pidx = t;
  }
  rbuf[t] = pv;
  ribuf[t] = pidx;
  __syncthreads();
  for (int s = 128; s > 0; s >>= 1) {
    if (t < s) {
      float ov = rbuf[t + s];
      int oi = ribuf[t + s];
      if (ov > rbuf[t] || (ov == rbuf[t] && oi < ribuf[t])) {
        rbuf[t] = ov;
        ribuf[t] = oi;
      }
    }
    __syncthreads();
  }
  int idx = ribuf[0];
  int r0 = idx / PEW, c0 = idx % PEW;
  __syncthreads();

  float lw = 0.f;
  if (t < KW * KW) {
    int i = t / KW, j = t % KW;
    lw = sfe[(r0 + i) * EDGE + (c0 + j)];
  }
  rbuf[t] = lw;
  __syncthreads();
  for (int s = 128; s > 0; s >>= 1) {
    if (t < s) rbuf[t] += rbuf[t + s];
    __syncthreads();
  }
  float w = rbuf[0] * invZ;
  __syncthreads();

  for (int idx2 = t; idx2 < 36 * (HD / 4); idx2 += 256) {
    int cell = idx2 >> 5;
    int c4 = idx2 & 31;
    int cc = g * 36 + cell;
    int i = cc / 12, j = cc % 12;
    int s = OFF + (r0 + i) * EDGE + (c0 + j);
    *(float4*)&win[cell][c4 * 4] =
        *(const float4*)(hid + ((size_t)(b * SLEN + s)) * HID + h * HD + c4 * 4);
  }
  __syncthreads();

  float acc0[36], acc1[36];
#pragma unroll
  for (int cell = 0; cell < 36; ++cell) { acc0[cell] = 0.f; acc1[cell] = 0.f; }

  int e0 = t, e1 = t + 256;
  const float* w0 = Wup + (size_t)e0 * HD;
  const float* w1 = Wup + (size_t)e1 * HD;
  for (int c = 0; c < 32; ++c) {
    float4 u0 = *(const float4*)(w0 + c * 4);
    float4 u1 = *(const float4*)(w1 + c * 4);
#pragma unroll
    for (int cell = 0; cell < 36; ++cell) {
      float4 qv = *(const float4*)&win[cell][c * 4];
      acc0[cell] += dot4(qv, u0);
      acc1[cell] += dot4(qv, u1);
    }
  }

  int si0 = e0 >> 8, sj0 = (e0 >> 7) & 1, d0 = e0 & 127;
  int si1 = e1 >> 8, sj1 = (e1 >> 7) & 1, d1 = e1 & 127;
#pragma unroll
  for (int cell = 0; cell < 36; ++cell) {
    int cc = g * 36 + cell;
    int i = cc / 12, j = cc % 12;
    {
      int srow = OFF + (2 * i + si0) * EDGE + (2 * j + sj0);
      hs[((size_t)(b * SLEN + srow)) * HID + h * HD + d0] = f2bf(acc0[cell] * w);
    }
    {
      int srow = OFF + (2 * i + si1) * EDGE + (2 * j + sj1);
      hs[((size_t)(b * SLEN + srow)) * HID + h * HD + d1] = f2bf(acc1[cell] * w);
    }
  }
}

// ---------------- Kernel E: 16-wave single-barrier counted-vmcnt bf16 MFMA GEMM ----------------
// Round-9 protocol at 1024 threads: BM=128, BN=256, BK=64; 256 blocks (1/CU),
// 16 waves (4 per SIMD — 2x latency hiding), per-wave 32x64 C (acc 2x4).
// Staging 3 loads/thread (1 A + 2 B) -> steady-state vmcnt(3). Triple-buffered
// LDS, resid register-prefetch at kt==62.
__global__ __launch_bounds__(1024, 1) void k_gemm(const unsigned short* __restrict__ A,
                                                  const unsigned short* __restrict__ Bm,
                                                  const float* __restrict__ resid,
                                                  float* __restrict__ out) {
  __shared__ unsigned short lA[3][128 * 64];   // 48 KB
  __shared__ unsigned short lB[3][256 * 64];   // 96 KB

  int bid0 = blockIdx.x;
  int swz = (bid0 & 7) * 32 + (bid0 >> 3);     // XCD-contiguous (256 % 8 == 0)
  int bm0 = (swz & 15) << 7;
  int bn0 = (swz >> 4) << 8;                   // each XCD: 512-col B slice = 4 MB L2
  int t = threadIdx.x;
  int ln = t & 63, wv = t >> 6;
  int wr = wv >> 2, wc = wv & 3;               // 4 x 4 wave grid, 32x64 C per wave

  int aOff[2][2], bOff[4][2];
#pragma unroll
  for (int ks = 0; ks < 2; ++ks) {
    int ga = ks * 4 + (ln >> 4);
#pragma unroll
    for (int q = 0; q < 2; ++q) {
      int ra = wr * 32 + q * 16 + (ln & 15);
      aOff[q][ks] = ra * 64 + ((ga ^ (ra & 7)) * 8);
    }
#pragma unroll
    for (int q = 0; q < 4; ++q) {
      int rb = wc * 64 + q * 16 + (ln & 15);
      bOff[q][ks] = rb * 64 + ((ga ^ (rb & 7)) * 8);
    }
  }

  // staging: A granule t (1024 total); B granules t and t+1024 (2048 total)
  const unsigned short *aS0, *bS0, *bS1;
  unsigned short *aD0, *bD0, *bD1;
  {
    int G = t, r = G >> 3, g = G & 7;
    aS0 = A + (size_t)(bm0 + r) * HID + ((g ^ (r & 7)) * 8);
    aD0 = &lA[0][0] + G * 8;
    bS0 = Bm + (size_t)(bn0 + r) * HID + ((g ^ (r & 7)) * 8);
    bD0 = &lB[0][0] + G * 8;
    G = t + 1024; r = G >> 3; g = G & 7;
    bS1 = Bm + (size_t)(bn0 + r) * HID + ((g ^ (r & 7)) * 8);
    bD1 = &lB[0][0] + G * 8;
  }

#define STAGE_ALL(kt_, nb_)                                \
  load_lds16(aS0 + (kt_) * 64, aD0 + (nb_) * 8192);        \
  load_lds16(bS0 + (kt_) * 64, bD0 + (nb_) * 16384);       \
  load_lds16(bS1 + (kt_) * 64, bD1 + (nb_) * 16384);

  f32x4 acc[2][4];
#pragma unroll
  for (int mi = 0; mi < 2; ++mi)
#pragma unroll
    for (int ni = 0; ni < 4; ++ni) acc[mi][ni] = (f32x4){0.f, 0.f, 0.f, 0.f};

  f32x4 rv[2][4];   // resid prefetch (written at kt==62, consumed in epilogue)

  STAGE_ALL(0, 0);
  STAGE_ALL(1, 1);

  int cur = 0;
  for (int kt = 0; kt < 64; ++kt) {
    if (kt < 63) {
      asm volatile("s_waitcnt vmcnt(3)" ::: "memory");
    } else {
      asm volatile("s_waitcnt vmcnt(0)" ::: "memory");
    }
    __builtin_amdgcn_s_barrier();

    const unsigned short* Ab = &lA[0][0] + cur * 8192;
    const unsigned short* Bb = &lB[0][0] + cur * 16384;

    bf16x8 aF[2][2], bF[4][2];
#pragma unroll
    for (int q = 0; q < 2; ++q) {
      aF[q][0] = *(const bf16x8*)(Ab + aOff[q][0]);
      aF[q][1] = *(const bf16x8*)(Ab + aOff[q][1]);
    }
#pragma unroll
    for (int q = 0; q < 4; ++q) {
      bF[q][0] = *(const bf16x8*)(Bb + bOff[q][0]);
      bF[q][1] = *(const bf16x8*)(Bb + bOff[q][1]);
    }

    int nb = cur + 2; if (nb >= 3) nb -= 3;
    if (kt < 62) { STAGE_ALL(kt + 2, nb); }

    if (kt == 62) {
#pragma unroll
      for (int mi = 0; mi < 2; ++mi)
#pragma unroll
        for (int ni = 0; ni < 4; ++ni) {
          int m = bm0 + wr * 32 + mi * 16 + (ln >> 4) * 4;
          int n = bn0 + wc * 64 + ni * 16 + (ln & 15);
#pragma unroll
          for (int r = 0; r < 4; ++r)
            rv[mi][ni][r] = resid[(size_t)(m + r) * HID + n];
        }
    }

    __builtin_amdgcn_s_setprio(1);
#pragma unroll
    for (int ni = 0; ni < 4; ++ni)
#pragma unroll
      for (int mi = 0; mi < 2; ++mi) {
        acc[mi][ni] = __builtin_amdgcn_mfma_f32_16x16x32_bf16(aF[mi][0], bF[ni][0],
                                                              acc[mi][ni], 0, 0, 0);
        acc[mi][ni] = __builtin_amdgcn_mfma_f32_16x16x32_bf16(aF[mi][1], bF[ni][1],
                                                              acc[mi][ni], 0, 0, 0);
      }
    __builtin_amdgcn_s_setprio(0);

    cur = cur + 1; if (cur >= 3) cur = 0;
  }
#undef STAGE_ALL

#pragma unroll
  for (int mi = 0; mi < 2; ++mi) {
#pragma unroll
    for (int ni = 0; ni < 4; ++ni) {
      int m = bm0 + wr * 32 + mi * 16 + (ln >> 4) * 4;
      int n = bn0 + wc * 64 + ni * 16 + (ln & 15);
#pragma unroll
      for (int r = 0; r < 4; ++r) {
        float x = acc[mi][ni][r];
        float s = x / (1.f + __expf(-x));
        size_t o = (size_t)(m + r) * HID + n;
        out[o] = rv[mi][ni][r] + s;
      }
    }
  }
}

extern "C" void kernel_launch(void* const* d_in, const int* in_sizes, int n_in,
                              void* d_out, int out_size, void* d_ws, size_t ws_size,
                              hipStream_t stream) {
  const float* hid = (const float*)d_in[0];
  const float* Win = (const float*)d_in[1];
  const float* Wup = (const float*)d_in[2];
  float* out = (float*)d_out;
  char* ws = (char*)d_ws;

  unsigned short* Wb  = (unsigned short*)ws;                 // 33,554,432 B
  unsigned short* Phi = (unsigned short*)(ws + 33554432);    // 16,777,216 B
  float* part = (float*)(ws + 50331648);                     //  1,032,192 B
  unsigned short* Plo = (unsigned short*)d_out;  // lo plane lives in d_out until k_gemm

  k_prep<<<2048, 256, 0, stream>>>(hid, Phi, Plo);
  k_scores<<<NSB + NWB, 512, 0, stream>>>(Phi, Plo, part, Win, Wb);
  k_himg<<<NB * NH * 4, 256, 0, stream>>>(part, hid, Wup, Phi);
  k_gemm<<<256, 1024, 0, stream>>>(Phi, Wb, hid, out);
}

// Round 21
// 170.091 us; speedup vs baseline: 1.0842x; 1.0842x over previous
//
#include <hip/hip_runtime.h>
#include <hip/hip_bf16.h>
#include <math.h>

#define HID 4096
#define NH 32
#define HD 128
#define EDGE 24
#define KW 12
#define PEW 13
#define VT 576
#define OFF 5
#define NB 2
#define SLEN 1024
#define QT 64      // q rows per scores block
#define NQT 7      // q tiles per (b,h)  (448/64)
#define KT 64      // k rows per staged tile
#define NKT 16     // 1024/KT
#define NSB 448    // scores blocks (64 bh x 7 qt)
#define NWB 128    // W-convert blocks folded into k_scores' grid

typedef short bf16x8 __attribute__((ext_vector_type(8)));
typedef float f32x4 __attribute__((ext_vector_type(4)));
typedef unsigned int u32;

static __device__ __forceinline__ unsigned short f2bf(float f) {
  union { float f; u32 u; } v; v.f = f;
  u32 u = v.u;
  return (unsigned short)((u + 0x7fffu + ((u >> 16) & 1u)) >> 16);
}

static __device__ __forceinline__ float dot4(float4 a, float4 b) {
  return a.x * b.x + a.y * b.y + a.z * b.z + a.w * b.w;
}

static __device__ __forceinline__ void load_lds16(const void* g, void* l) {
  __builtin_amdgcn_global_load_lds((const __attribute__((address_space(1))) u32*)g,
                                   (__attribute__((address_space(3))) u32*)l, 16, 0, 0);
}

// ---------------- Kernel PREP: hidden -> hi/lo bf16 planes (grid-stride) ----------------
// Plo written only for NON-image rows (the only rows whose lo plane is read).
__global__ __launch_bounds__(256) void k_prep(const float* __restrict__ hid,
                                              unsigned short* __restrict__ Phi,
                                              unsigned short* __restrict__ Plo) {
  const int STR = 2048 * 256;
  int t0 = blockIdx.x * 256 + threadIdx.x;
  for (int i = t0; i < NB * SLEN * HID / 4; i += STR) {
    float4 x = ((const float4*)hid)[i];
    float e[4] = {x.x, x.y, x.z, x.w};
    ushort4 hv, lv;
    unsigned short* hp = (unsigned short*)&hv;
    unsigned short* lp = (unsigned short*)&lv;
#pragma unroll
    for (int j = 0; j < 4; ++j) {
      u32 u = __float_as_uint(e[j]);
      u32 hb = (u + 0x7fffu + ((u >> 16) & 1u)) >> 16;
      float r = e[j] - __uint_as_float(hb << 16);
      u32 ur = __float_as_uint(r);
      u32 lb = (ur + 0x7fffu + ((ur >> 16) & 1u)) >> 16;
      hp[j] = (unsigned short)hb;
      lp[j] = (unsigned short)lb;
    }
    ((ushort4*)Phi)[i] = hv;
    int s = (i >> 10) & (SLEN - 1);
    if (s < OFF || s >= OFF + VT) ((ushort4*)Plo)[i] = lv;
  }
}

// ---------------- Kernel B: single-pass 8-wave MFMA scores (2-chain) + W-convert ----------------
// blocks [0, 448): scores (b,h,qt); blocks [448, 576): W_in f32 -> bf16.
__global__ __launch_bounds__(512, 2) void k_scores(const unsigned short* __restrict__ Phi,
                                                   const unsigned short* __restrict__ Plo,
                                                   float* __restrict__ part,
                                                   const float* __restrict__ Win,
                                                   unsigned short* __restrict__ Wb) {
  __shared__ unsigned short Kh[3][KT * HD];   // 48 KB
  __shared__ float cs[4][SLEN];               // 16 KB
  __shared__ float zbuf[2][QT];               // 512 B

  int bid = blockIdx.x;
  int t = threadIdx.x;

  if (bid >= NSB) {
    int base = (bid - NSB) * 32768;
#pragma unroll 4
    for (int it = 0; it < 64; ++it) {
      int i = base + it * 512 + t;
      float4 v = ((const float4*)Win)[i];
      ushort4 o;
      o.x = f2bf(v.x); o.y = f2bf(v.y); o.z = f2bf(v.z); o.w = f2bf(v.w);
      ((ushort4*)Wb)[i] = o;
    }
    return;
  }

  int xcd = bid & 7, idx = bid >> 3;          // idx in 0..55
  int bh = xcd * 8 + idx / NQT;
  int qt = idx % NQT;
  int b = bh >> 5, h = bh & 31;
  int l = t & 63, wv = t >> 6;
  int wq = wv >> 1, wk = wv & 1;

  const unsigned short* PhB = Phi + (size_t)b * SLEN * HID + h * HD;
  const unsigned short* PlB = Plo + (size_t)b * SLEN * HID + h * HD;

  bf16x8 qhi[4], qlo[4];
  {
    int ql = qt * QT + wq * 16 + (l & 15);
    int qg = (ql < OFF) ? ql : ql + VT;
    const unsigned short* ph = PhB + (size_t)qg * HID + (l >> 4) * 8;
    const unsigned short* pl = PlB + (size_t)qg * HID + (l >> 4) * 8;
#pragma unroll
    for (int ds = 0; ds < 4; ++ds) {
      qhi[ds] = *(const bf16x8*)(ph + ds * 32);
      qlo[ds] = *(const bf16x8*)(pl + ds * 32);
    }
  }

  int g0 = t, g1 = t + 512;
  int r0g = g0 >> 4, r1g = g1 >> 4;
  size_t soff0 = (size_t)r0g * HID + ((g0 & 15) ^ (r0g & 7)) * 8;
  size_t soff1 = (size_t)r1g * HID + ((g1 & 15) ^ (r1g & 7)) * 8;

#define STAGE(kt_, bb_)                                                        \
  do {                                                                         \
    size_t kb_ = (size_t)(kt_)*KT * HID;                                       \
    load_lds16(PhB + kb_ + soff0, &Kh[bb_][g0 * 8]);                           \
    load_lds16(PhB + kb_ + soff1, &Kh[bb_][g1 * 8]);                           \
  } while (0)

  const float scale = 0.088388347648318447f;  // 1/sqrt(128)

  int foff[2][4];
#pragma unroll
  for (int c = 0; c < 2; ++c) {
    int rb = wk * 32 + c * 16 + (l & 15);
#pragma unroll
    for (int ds = 0; ds < 4; ++ds)
      foff[c][ds] = rb * HD + (((ds * 4) + (l >> 4)) ^ (rb & 7)) * 8;
  }

  float e[NKT][2][4];

  STAGE(0, 0);
  STAGE(1, 1);

#pragma unroll
  for (int tt = 0; tt < NKT; ++tt) {
    int bb = tt % 3;
    if (tt < NKT - 1) {
      asm volatile("s_waitcnt vmcnt(2)" ::: "memory");
    } else {
      asm volatile("s_waitcnt vmcnt(0)" ::: "memory");
    }
    __builtin_amdgcn_s_barrier();
    __builtin_amdgcn_sched_barrier(0);

    bf16x8 kh[2][4];
#pragma unroll
    for (int c = 0; c < 2; ++c)
#pragma unroll
      for (int ds = 0; ds < 4; ++ds)
        kh[c][ds] = *(const bf16x8*)&Kh[bb][foff[c][ds]];
    if (tt + 2 < NKT) STAGE(tt + 2, (tt + 2) % 3);

#pragma unroll
    for (int c = 0; c < 2; ++c) {
      f32x4 aP = {0.f, 0.f, 0.f, 0.f};
      f32x4 aR = {0.f, 0.f, 0.f, 0.f};
#pragma unroll
      for (int ds = 0; ds < 4; ++ds) {
        aP = __builtin_amdgcn_mfma_f32_16x16x32_bf16(qhi[ds], kh[c][ds], aP, 0, 0, 0);
        aR = __builtin_amdgcn_mfma_f32_16x16x32_bf16(qlo[ds], kh[c][ds], aR, 0, 0, 0);
      }
#pragma unroll
      for (int jj = 0; jj < 4; ++jj)
        e[tt][c][jj] = __expf((aP[jj] + aR[jj]) * scale);
    }
  }
#undef STAGE

  float zr[4] = {0.f, 0.f, 0.f, 0.f};
#pragma unroll
  for (int tt = 0; tt < NKT; ++tt)
#pragma unroll
    for (int c = 0; c < 2; ++c)
#pragma unroll
      for (int jj = 0; jj < 4; ++jj) zr[jj] += e[tt][c][jj];
#pragma unroll
  for (int jj = 0; jj < 4; ++jj) {
    float z = zr[jj];
    z += __shfl_xor(z, 1);
    z += __shfl_xor(z, 2);
    z += __shfl_xor(z, 4);
    z += __shfl_xor(z, 8);
    zr[jj] = z;
  }
  if ((l & 15) == 0) {
#pragma unroll
    for (int jj = 0; jj < 4; ++jj)
      zbuf[wk][wq * 16 + (l >> 4) * 4 + jj] = zr[jj];
  }
  __syncthreads();

  float zinv[4];
#pragma unroll
  for (int jj = 0; jj < 4; ++jj) {
    int row = wq * 16 + (l >> 4) * 4 + jj;
    zinv[jj] = 1.f / (zbuf[0][row] + zbuf[1][row]);
  }

#pragma unroll
  for (int tt = 0; tt < NKT; ++tt)
#pragma unroll
    for (int c = 0; c < 2; ++c) {
      float v = e[tt][c][0] * zinv[0] + e[tt][c][1] * zinv[1] +
                e[tt][c][2] * zinv[2] + e[tt][c][3] * zinv[3];
      v += __shfl_xor(v, 16);
      v += __shfl_xor(v, 32);
      if (l < 16) cs[wq][tt * KT + wk * 32 + c * 16 + l] = v;
    }
  __syncthreads();

  for (int c5 = t; c5 < VT; c5 += 512) {
    int col = OFF + c5;
    part[((size_t)bh * NQT + qt) * VT + c5] =
        (cs[0][col] + cs[1][col]) + (cs[2][col] + cs[3][col]);
  }
}

// ---------------- Kernel D: fused head-reduce + window up-projection ----------------
__global__ __launch_bounds__(256) void k_himg(const float* __restrict__ part,
                                              const float* __restrict__ hid,
                                              const float* __restrict__ Wup,
                                              unsigned short* __restrict__ hs) {
  int bid = blockIdx.x;
  int g = bid & 3;
  int bh = bid >> 2;
  int b = bh / NH, h = bh % NH;
  int t = threadIdx.x;

  __shared__ float ia[VT];
  __shared__ float sfe[VT];
  __shared__ float rbuf[256];
  __shared__ int ribuf[256];
  __shared__ float win[36][HD];

  for (int i = t; i < VT; i += 256) {
    float s = 0.f;
    const float* p = part + (size_t)bh * NQT * VT + i;
    for (int c = 0; c < NQT; ++c) s += p[(size_t)c * VT];
    ia[i] = s;
  }
  __syncthreads();

  float lm = -1e30f;
  for (int i = t; i < VT; i += 256) lm = fmaxf(lm, ia[i]);
  rbuf[t] = lm;
  __syncthreads();
  for (int s = 128; s > 0; s >>= 1) {
    if (t < s) rbuf[t] = fmaxf(rbuf[t], rbuf[t + s]);
    __syncthreads();
  }
  float M = rbuf[0];
  __syncthreads();

  float lz = 0.f;
  for (int i = t; i < VT; i += 256) {
    float e = __expf(ia[i] - M);
    sfe[i] = e;
    lz += e;
  }
  rbuf[t] = lz;
  __syncthreads();
  for (int s = 128; s > 0; s >>= 1) {
    if (t < s) rbuf[t] += rbuf[t + s];
    __syncthreads();
  }
  float invZ = 1.f / rbuf[0];
  __syncthreads();

  float pv = -1e30f;
  int pidx = 0x7fffffff;
  if (t < PEW * PEW) {
    int r = t / PEW, c = t % PEW;
    float s = 0.f;
    for (int i = 0; i < KW; ++i)
      for (int j = 0; j < KW; ++j) s += ia[(r + i) * EDGE + (c + j)];
    pv = s;
    pidx = t;
  }
  rbuf[t] = pv;
  ribuf[t] = pidx;
  __syncthreads();
  for (int s = 128; s > 0; s >>= 1) {
    if (t < s) {
      float ov = rbuf[t + s];
      int oi = ribuf[t + s];
      if (ov > rbuf[t] || (ov == rbuf[t] && oi < ribuf[t])) {
        rbuf[t] = ov;
        ribuf[t] = oi;
      }
    }
    __syncthreads();
  }
  int idx = ribuf[0];
  int r0 = idx / PEW, c0 = idx % PEW;
  __syncthreads();

  float lw = 0.f;
  if (t < KW * KW) {
    int i = t / KW, j = t % KW;
    lw = sfe[(r0 + i) * EDGE + (c0 + j)];
  }
  rbuf[t] = lw;
  __syncthreads();
  for (int s = 128; s > 0; s >>= 1) {
    if (t < s) rbuf[t] += rbuf[t + s];
    __syncthreads();
  }
  float w = rbuf[0] * invZ;
  __syncthreads();

  for (int idx2 = t; idx2 < 36 * (HD / 4); idx2 += 256) {
    int cell = idx2 >> 5;
    int c4 = idx2 & 31;
    int cc = g * 36 + cell;
    int i = cc / 12, j = cc % 12;
    int s = OFF + (r0 + i) * EDGE + (c0 + j);
    *(float4*)&win[cell][c4 * 4] =
        *(const float4*)(hid + ((size_t)(b * SLEN + s)) * HID + h * HD + c4 * 4);
  }
  __syncthreads();

  float acc0[36], acc1[36];
#pragma unroll
  for (int cell = 0; cell < 36; ++cell) { acc0[cell] = 0.f; acc1[cell] = 0.f; }

  int e0 = t, e1 = t + 256;
  const float* w0 = Wup + (size_t)e0 * HD;
  const float* w1 = Wup + (size_t)e1 * HD;
  for (int c = 0; c < 32; ++c) {
    float4 u0 = *(const float4*)(w0 + c * 4);
    float4 u1 = *(const float4*)(w1 + c * 4);
#pragma unroll
    for (int cell = 0; cell < 36; ++cell) {
      float4 qv = *(const float4*)&win[cell][c * 4];
      acc0[cell] += dot4(qv, u0);
      acc1[cell] += dot4(qv, u1);
    }
  }

  int si0 = e0 >> 8, sj0 = (e0 >> 7) & 1, d0 = e0 & 127;
  int si1 = e1 >> 8, sj1 = (e1 >> 7) & 1, d1 = e1 & 127;
#pragma unroll
  for (int cell = 0; cell < 36; ++cell) {
    int cc = g * 36 + cell;
    int i = cc / 12, j = cc % 12;
    {
      int srow = OFF + (2 * i + si0) * EDGE + (2 * j + sj0);
      hs[((size_t)(b * SLEN + srow)) * HID + h * HD + d0] = f2bf(acc0[cell] * w);
    }
    {
      int srow = OFF + (2 * i + si1) * EDGE + (2 * j + sj1);
      hs[((size_t)(b * SLEN + srow)) * HID + h * HD + d1] = f2bf(acc1[cell] * w);
    }
  }
}

// ---------------- Kernel E: single-barrier counted-vmcnt bf16 MFMA GEMM ----------------
// ROUND-19 VERBATIM: round-9 protocol + resid register-prefetch at kt==62.
// Measured 87-88 us warm, MfmaUtil ~33%, 0 conflicts.
__global__ __launch_bounds__(512, 2) void k_gemm(const unsigned short* __restrict__ A,
                                                 const unsigned short* __restrict__ Bm,
                                                 const float* __restrict__ resid,
                                                 float* __restrict__ out) {
  __shared__ unsigned short lA[3][128 * 64];   // 48 KB
  __shared__ unsigned short lB[3][256 * 64];   // 96 KB

  int bid0 = blockIdx.x;
  int swz = (bid0 & 7) * 32 + (bid0 >> 3);     // XCD-contiguous (256 % 8 == 0)
  int bm0 = (swz & 15) << 7;
  int bn0 = (swz >> 4) << 8;                   // each XCD: 512-col B slice = 4 MB L2
  int t = threadIdx.x;
  int ln = t & 63, wv = t >> 6;
  int wr = wv >> 2, wc = wv & 3;               // 2 x 4 wave grid, 64x64 C per wave

  int aOff[4][2], bOff[4][2];
#pragma unroll
  for (int q = 0; q < 4; ++q)
#pragma unroll
    for (int ks = 0; ks < 2; ++ks) {
      int ga = ks * 4 + (ln >> 4);
      int ra = wr * 64 + q * 16 + (ln & 15);
      aOff[q][ks] = ra * 64 + ((ga ^ (ra & 7)) * 8);
      int rb = wc * 64 + q * 16 + (ln & 15);
      bOff[q][ks] = rb * 64 + ((ga ^ (rb & 7)) * 8);
    }

  const unsigned short* aS0; const unsigned short* aS1;
  unsigned short *aD0, *aD1;
  {
    int G = t, r = G >> 3, g = G & 7;
    aS0 = A + (size_t)(bm0 + r) * HID + ((g ^ (r & 7)) * 8);
    aD0 = &lA[0][0] + G * 8;
    G = t + 512; r = G >> 3; g = G & 7;
    aS1 = A + (size_t)(bm0 + r) * HID + ((g ^ (r & 7)) * 8);
    aD1 = &lA[0][0] + G * 8;
  }
  const unsigned short *bS0, *bS1, *bS2, *bS3;
  unsigned short *bD0, *bD1, *bD2, *bD3;
  {
    int G = t, r = G >> 3, g = G & 7;
    bS0 = Bm + (size_t)(bn0 + r) * HID + ((g ^ (r & 7)) * 8);
    bD0 = &lB[0][0] + G * 8;
    G = t + 512; r = G >> 3; g = G & 7;
    bS1 = Bm + (size_t)(bn0 + r) * HID + ((g ^ (r & 7)) * 8);
    bD1 = &lB[0][0] + G * 8;
    G = t + 1024; r = G >> 3; g = G & 7;
    bS2 = Bm + (size_t)(bn0 + r) * HID + ((g ^ (r & 7)) * 8);
    bD2 = &lB[0][0] + G * 8;
    G = t + 1536; r = G >> 3; g = G & 7;
    bS3 = Bm + (size_t)(bn0 + r) * HID + ((g ^ (r & 7)) * 8);
    bD3 = &lB[0][0] + G * 8;
  }

#define STAGE_ALL(kt_, nb_)                                \
  load_lds16(aS0 + (kt_) * 64, aD0 + (nb_) * 8192);        \
  load_lds16(aS1 + (kt_) * 64, aD1 + (nb_) * 8192);        \
  load_lds16(bS0 + (kt_) * 64, bD0 + (nb_) * 16384);       \
  load_lds16(bS1 + (kt_) * 64, bD1 + (nb_) * 16384);       \
  load_lds16(bS2 + (kt_) * 64, bD2 + (nb_) * 16384);       \
  load_lds16(bS3 + (kt_) * 64, bD3 + (nb_) * 16384);

  f32x4 acc[4][4];
#pragma unroll
  for (int mi = 0; mi < 4; ++mi)
#pragma unroll
    for (int ni = 0; ni < 4; ++ni) acc[mi][ni] = (f32x4){0.f, 0.f, 0.f, 0.f};

  f32x4 rv[4][4];   // resid prefetch (written at kt==62, consumed in epilogue)

  STAGE_ALL(0, 0);
  STAGE_ALL(1, 1);

  int cur = 0;
  for (int kt = 0; kt < 64; ++kt) {
    if (kt < 63) {
      asm volatile("s_waitcnt vmcnt(6)" ::: "memory");
    } else {
      asm volatile("s_waitcnt vmcnt(0)" ::: "memory");
    }
    __builtin_amdgcn_s_barrier();

    const unsigned short* Ab = &lA[0][0] + cur * 8192;
    const unsigned short* Bb = &lB[0][0] + cur * 16384;

    bf16x8 aF[4][2], bF[4][2];
#pragma unroll
    for (int q = 0; q < 4; ++q) {
      aF[q][0] = *(const bf16x8*)(Ab + aOff[q][0]);
      aF[q][1] = *(const bf16x8*)(Ab + aOff[q][1]);
      bF[q][0] = *(const bf16x8*)(Bb + bOff[q][0]);
      bF[q][1] = *(const bf16x8*)(Bb + bOff[q][1]);
    }

    int nb = cur + 2; if (nb >= 3) nb -= 3;
    if (kt < 62) { STAGE_ALL(kt + 2, nb); }

    if (kt == 62) {
      // issue resid loads ~1 tile (~3300 cyc) before the kt=63 vmcnt(0):
      // they land inside the drain; epilogue becomes pure FMA+store.
#pragma unroll
      for (int mi = 0; mi < 4; ++mi)
#pragma unroll
        for (int ni = 0; ni < 4; ++ni) {
          int m = bm0 + wr * 64 + mi * 16 + (ln >> 4) * 4;
          int n = bn0 + wc * 64 + ni * 16 + (ln & 15);
#pragma unroll
          for (int r = 0; r < 4; ++r)
            rv[mi][ni][r] = resid[(size_t)(m + r) * HID + n];
        }
    }

    __builtin_amdgcn_s_setprio(1);
#pragma unroll
    for (int ni = 0; ni < 4; ++ni)
#pragma unroll
      for (int mi = 0; mi < 4; ++mi) {
        acc[mi][ni] = __builtin_amdgcn_mfma_f32_16x16x32_bf16(aF[mi][0], bF[ni][0],
                                                              acc[mi][ni], 0, 0, 0);
        acc[mi][ni] = __builtin_amdgcn_mfma_f32_16x16x32_bf16(aF[mi][1], bF[ni][1],
                                                              acc[mi][ni], 0, 0, 0);
      }
    __builtin_amdgcn_s_setprio(0);

    cur = cur + 1; if (cur >= 3) cur = 0;
  }
#undef STAGE_ALL

#pragma unroll
  for (int mi = 0; mi < 4; ++mi) {
#pragma unroll
    for (int ni = 0; ni < 4; ++ni) {
      int m = bm0 + wr * 64 + mi * 16 + (ln >> 4) * 4;
      int n = bn0 + wc * 64 + ni * 16 + (ln & 15);
#pragma unroll
      for (int r = 0; r < 4; ++r) {
        float x = acc[mi][ni][r];
        float s = x / (1.f + __expf(-x));
        size_t o = (size_t)(m + r) * HID + n;
        out[o] = rv[mi][ni][r] + s;
      }
    }
  }
}

extern "C" void kernel_launch(void* const* d_in, const int* in_sizes, int n_in,
                              void* d_out, int out_size, void* d_ws, size_t ws_size,
                              hipStream_t stream) {
  const float* hid = (const float*)d_in[0];
  const float* Win = (const float*)d_in[1];
  const float* Wup = (const float*)d_in[2];
  float* out = (float*)d_out;
  char* ws = (char*)d_ws;

  unsigned short* Wb  = (unsigned short*)ws;                 // 33,554,432 B
  unsigned short* Phi = (unsigned short*)(ws + 33554432);    // 16,777,216 B
  float* part = (float*)(ws + 50331648);                     //  1,032,192 B
  unsigned short* Plo = (unsigned short*)d_out;  // lo plane lives in d_out until k_gemm

  k_prep<<<2048, 256, 0, stream>>>(hid, Phi, Plo);
  k_scores<<<NSB + NWB, 512, 0, stream>>>(Phi, Plo, part, Win, Wb);
  k_himg<<<NB * NH * 4, 256, 0, stream>>>(part, hid, Wup, Phi);
  k_gemm<<<256, 512, 0, stream>>>(Phi, Wb, hid, out);
}